// Round 1
// baseline (164716.479 us; speedup 1.0000x reference)
//
#include <hip/hip_runtime.h>

#define L_SEQ 4096
#define I_DIM 512
#define H_DIM 2048
#define O_DIM 512
#define NBLK  256
#define NTHR  512

typedef _Float16 h2 __attribute__((ext_vector_type(2)));
typedef float    f4 __attribute__((ext_vector_type(4)));

struct __attribute__((aligned(16))) H4 { h2 v[4]; };

__device__ __forceinline__ float fdot2_(h2 a, h2 b, float c) {
#if __has_builtin(__builtin_amdgcn_fdot2)
  return __builtin_amdgcn_fdot2(a, b, c, false);
#else
  return c + (float)a[0] * (float)b[0] + (float)a[1] * (float)b[1];
#endif
}

struct WRegs {
  h2 w[3][5][4];     // [gate r/z/n][k-segment 0..4][pair]  seg0 = W_ih, seg1..4 = W_hh
  float bi[3], bh[3];
};

__device__ __forceinline__ void load_weights(WRegs& W, int j, int lane,
    const float* __restrict__ w_ih, const float* __restrict__ w_hh,
    const float* __restrict__ b_ih, const float* __restrict__ b_hh) {
#pragma unroll
  for (int g = 0; g < 3; ++g) {
    const float* rih = w_ih + ((size_t)g * H_DIM + j) * I_DIM + lane * 8;
#pragma unroll
    for (int hh = 0; hh < 2; ++hh) {
      f4 a = *(const f4*)(rih + 4 * hh);
      W.w[g][0][2*hh+0] = h2{(_Float16)a[0], (_Float16)a[1]};
      W.w[g][0][2*hh+1] = h2{(_Float16)a[2], (_Float16)a[3]};
    }
    const float* rhh = w_hh + ((size_t)g * H_DIM + j) * H_DIM + lane * 8;
#pragma unroll
    for (int s = 1; s < 5; ++s) {
#pragma unroll
      for (int hh = 0; hh < 2; ++hh) {
        f4 a = *(const f4*)(rhh + (s - 1) * 512 + 4 * hh);
        W.w[g][s][2*hh+0] = h2{(_Float16)a[0], (_Float16)a[1]};
        W.w[g][s][2*hh+1] = h2{(_Float16)a[2], (_Float16)a[3]};
      }
    }
    W.bi[g] = b_ih[g * H_DIM + j];
    W.bh[g] = b_hh[g * H_DIM + j];
  }
}

__device__ __forceinline__ void stage_h(_Float16* h_lds, const float* __restrict__ hsrc) {
  int t = threadIdx.x;
  if (t < 256) {
    f4 a = *(const f4*)(hsrc + t * 8);
    f4 b = *(const f4*)(hsrc + t * 8 + 4);
    H4 pk;
    pk.v[0] = h2{(_Float16)a[0], (_Float16)a[1]};
    pk.v[1] = h2{(_Float16)a[2], (_Float16)a[3]};
    pk.v[2] = h2{(_Float16)b[0], (_Float16)b[1]};
    pk.v[3] = h2{(_Float16)b[2], (_Float16)b[3]};
    *(H4*)(h_lds + t * 8) = pk;
  }
}

__device__ __forceinline__ void dot_h(const WRegs& W, const _Float16* h_lds, int lane,
                                      float& ar, float& az, float& anh) {
#pragma unroll
  for (int s = 1; s < 5; ++s) {
    H4 hh = *(const H4*)(h_lds + (s - 1) * 512 + lane * 8);
#pragma unroll
    for (int q = 0; q < 4; ++q) {
      ar  = fdot2_(W.w[0][s][q], hh.v[q], ar);
      az  = fdot2_(W.w[1][s][q], hh.v[q], az);
      anh = fdot2_(W.w[2][s][q], hh.v[q], anh);
    }
  }
}

__device__ __forceinline__ void wave_red4(float& a, float& b, float& c, float& d) {
#pragma unroll
  for (int off = 32; off > 0; off >>= 1) {
    a += __shfl_xor(a, off, 64);
    b += __shfl_xor(b, off, 64);
    c += __shfl_xor(c, off, 64);
    d += __shfl_xor(d, off, 64);
  }
}

// Flag-array grid barrier: no atomic-counter serialization. Thread i (<NBLK)
// spins on flags[i]; release store orders the h stores (agent scope), acquire
// fence afterwards invalidates L1/L2 so the next h read hits fresh L3 data.
__device__ __forceinline__ void gbar(int* flags, int blk, int phase) {
  __syncthreads();   // vmcnt(0) drain: all this block's h/logit stores visible
  if (threadIdx.x == 0)
    __hip_atomic_store(&flags[blk], phase + 1, __ATOMIC_RELEASE, __HIP_MEMORY_SCOPE_AGENT);
  if (threadIdx.x < NBLK) {
    while (__hip_atomic_load(&flags[threadIdx.x], __ATOMIC_RELAXED,
                             __HIP_MEMORY_SCOPE_AGENT) <= phase)
      __builtin_amdgcn_s_sleep(1);
  }
  __syncthreads();
  __builtin_amdgcn_fence(__ATOMIC_ACQUIRE, "agent");
}

__global__ void __launch_bounds__(NTHR, 2) rnn_persistent(
    const float* __restrict__ input_,
    const float* __restrict__ ewih, const float* __restrict__ ewhh,
    const float* __restrict__ ebih, const float* __restrict__ ebhh,
    const float* __restrict__ dwih, const float* __restrict__ dwhh,
    const float* __restrict__ dbih, const float* __restrict__ dbhh,
    const float* __restrict__ h2ow, const float* __restrict__ h2ob,
    float* __restrict__ out, char* __restrict__ ws, int tdec)
{
  __shared__ alignas(16) _Float16 h_lds[H_DIM];
  __shared__ float red[16];
  __shared__ int   sidx[16];

  int*   flags  = (int*)ws;
  float* hbuf0  = (float*)(ws + 1024);
  float* hbuf1  = hbuf0 + H_DIM;
  float* logits = (float*)(ws + 1024 + 2 * H_DIM * 4);
  int*   idxp   = (int*)(ws + 1024 + 2 * H_DIM * 4 + O_DIM * 4);

  const int tid  = threadIdx.x;
  const int lane = tid & 63;
  const int wid  = tid >> 6;
  const int blk  = blockIdx.x;
  const int j    = blk * 8 + wid;     // hidden unit owned by this wave

  WRegs W;
  load_weights(W, j, lane, ewih, ewhh, ebih, ebhh);

  float hold = 0.f;   // exact fp32 carry of h_j
  int phase = 0;

  // ---------------- encoder ----------------
  for (int t = 0; t < L_SEQ; ++t) {
    float* hin  = (t & 1) ? hbuf1 : hbuf0;
    float* hout = (t & 1) ? hbuf0 : hbuf1;
    stage_h(h_lds, hin);
    const float* xr = input_ + (size_t)t * I_DIM + lane * 8;
    f4 xa = *(const f4*)xr;
    f4 xb = *(const f4*)(xr + 4);
    h2 xv[4] = { h2{(_Float16)xa[0], (_Float16)xa[1]}, h2{(_Float16)xa[2], (_Float16)xa[3]},
                 h2{(_Float16)xb[0], (_Float16)xb[1]}, h2{(_Float16)xb[2], (_Float16)xb[3]} };
    __syncthreads();

    float ar = 0.f, az = 0.f, anx = 0.f, anh = 0.f;
#pragma unroll
    for (int q = 0; q < 4; ++q) {
      ar  = fdot2_(W.w[0][0][q], xv[q], ar);
      az  = fdot2_(W.w[1][0][q], xv[q], az);
      anx = fdot2_(W.w[2][0][q], xv[q], anx);
    }
    dot_h(W, h_lds, lane, ar, az, anh);
    wave_red4(ar, az, anx, anh);

    float r = 1.f / (1.f + __expf(-(ar + W.bi[0] + W.bh[0])));
    float z = 1.f / (1.f + __expf(-(az + W.bi[1] + W.bh[1])));
    float n = tanhf(anx + W.bi[2] + r * (anh + W.bh[2]));
    hold = (1.f - z) * n + z * hold;
    if (lane == 0)
      __hip_atomic_store(&hout[j], hold, __ATOMIC_RELEASE, __HIP_MEMORY_SCOPE_AGENT);
    gbar(flags, blk, phase++);
  }

  // ---------------- decoder ----------------
  load_weights(W, j, lane, dwih, dwhh, dbih, dbhh);
  int db = 0;   // L_SEQ even -> h_enc sits in hbuf0

  for (int d = 0; d < tdec; ++d) {
    float* hin  = db ? hbuf1 : hbuf0;
    float* hout = db ? hbuf0 : hbuf1;

    int idx;
    if (d > 0) idx = *idxp; else idx = -1;   // one-hot feedback (zeros at d=0)

    stage_h(h_lds, hin);
    __syncthreads();

    float ar = 0.f, az = 0.f, anx = 0.f, anh = 0.f;
    if (idx >= 0 && lane == (idx >> 3)) {
      const int qq = (idx & 7) >> 1;
      const int pp = idx & 1;
#pragma unroll
      for (int q = 0; q < 4; ++q) if (q == qq) {
        ar  += pp ? (float)W.w[0][0][q][1] : (float)W.w[0][0][q][0];
        az  += pp ? (float)W.w[1][0][q][1] : (float)W.w[1][0][q][0];
        anx += pp ? (float)W.w[2][0][q][1] : (float)W.w[2][0][q][0];
      }
    }
    dot_h(W, h_lds, lane, ar, az, anh);
    wave_red4(ar, az, anx, anh);

    float r = 1.f / (1.f + __expf(-(ar + W.bi[0] + W.bh[0])));
    float z = 1.f / (1.f + __expf(-(az + W.bi[1] + W.bh[1])));
    float n = tanhf(anx + W.bi[2] + r * (anh + W.bh[2]));
    hold = (1.f - z) * n + z * hold;
    if (lane == 0)
      __hip_atomic_store(&hout[j], hold, __ATOMIC_RELEASE, __HIP_MEMORY_SCOPE_AGENT);
    gbar(flags, blk, phase++);

    // ---- logits: rows 2*blk, 2*blk+1 of h2o (512 rows over 256 blocks) ----
    {
      const int row = 2 * blk + (tid >> 8);
      const int kk  = (tid & 255) * 8;
      const float* wrow = h2ow + (size_t)row * H_DIM + kk;
      const float* hrow = hout + kk;
      f4 wa = *(const f4*)wrow, wb = *(const f4*)(wrow + 4);
      f4 ha = *(const f4*)hrow, hb = *(const f4*)(hrow + 4);
      float s = wa[0]*ha[0] + wa[1]*ha[1] + wa[2]*ha[2] + wa[3]*ha[3]
              + wb[0]*hb[0] + wb[1]*hb[1] + wb[2]*hb[2] + wb[3]*hb[3];
#pragma unroll
      for (int off = 32; off > 0; off >>= 1) s += __shfl_xor(s, off, 64);
      if (lane == 0) red[wid] = s;
      __syncthreads();
      if (tid == 0) {
        float v = red[0] + red[1] + red[2] + red[3] + h2ob[2 * blk];
        __hip_atomic_store(&logits[2 * blk], v, __ATOMIC_RELEASE, __HIP_MEMORY_SCOPE_AGENT);
      }
      if (tid == 256) {
        float v = red[4] + red[5] + red[6] + red[7] + h2ob[2 * blk + 1];
        __hip_atomic_store(&logits[2 * blk + 1], v, __ATOMIC_RELEASE, __HIP_MEMORY_SCOPE_AGENT);
      }
    }
    gbar(flags, blk, phase++);

    // ---- log-softmax + argmax on block 0 ----
    if (blk == 0) {
      float v = logits[tid];
      float m = v; int mi = tid;
#pragma unroll
      for (int off = 32; off > 0; off >>= 1) {
        float om = __shfl_xor(m, off, 64);
        int   oi = __shfl_xor(mi, off, 64);
        if (om > m || (om == m && oi < mi)) { m = om; mi = oi; }
      }
      if (lane == 0) { red[wid] = m; sidx[wid] = mi; }
      __syncthreads();
      float M = red[0]; int MI = sidx[0];
#pragma unroll
      for (int w2 = 1; w2 < 8; ++w2)
        if (red[w2] > M || (red[w2] == M && sidx[w2] < MI)) { M = red[w2]; MI = sidx[w2]; }
      float e = __expf(v - M);
      float ss = e;
#pragma unroll
      for (int off = 32; off > 0; off >>= 1) ss += __shfl_xor(ss, off, 64);
      __syncthreads();
      if (lane == 0) red[wid] = ss;
      __syncthreads();
      float S = red[0] + red[1] + red[2] + red[3] + red[4] + red[5] + red[6] + red[7];
      out[(size_t)d * O_DIM + tid] = v - M - __logf(S);
      if (tid == 0)
        __hip_atomic_store(idxp, MI, __ATOMIC_RELEASE, __HIP_MEMORY_SCOPE_AGENT);
    }
    gbar(flags, blk, phase++);
    db ^= 1;
  }
}

extern "C" void kernel_launch(void* const* d_in, const int* in_sizes, int n_in,
                              void* d_out, int out_size, void* d_ws, size_t ws_size,
                              hipStream_t stream) {
  const float* input_ = (const float*)d_in[0];
  const float* ewih   = (const float*)d_in[1];
  const float* ewhh   = (const float*)d_in[2];
  const float* ebih   = (const float*)d_in[3];
  const float* ebhh   = (const float*)d_in[4];
  const float* dwih   = (const float*)d_in[5];
  const float* dwhh   = (const float*)d_in[6];
  const float* dbih   = (const float*)d_in[7];
  const float* dbhh   = (const float*)d_in[8];
  const float* h2ow   = (const float*)d_in[9];
  const float* h2ob   = (const float*)d_in[10];
  float* out = (float*)d_out;
  char*  ws  = (char*)d_ws;
  int tdec = out_size / O_DIM;   // 30

  // zero flags + h double-buffer + logits + idx (ws is re-poisoned每 launch)
  hipMemsetAsync(d_ws, 0, 1024 + 2 * H_DIM * 4 + O_DIM * 4 + 64, stream);

  void* args[] = { (void*)&input_, (void*)&ewih, (void*)&ewhh, (void*)&ebih, (void*)&ebhh,
                   (void*)&dwih, (void*)&dwhh, (void*)&dbih, (void*)&dbhh,
                   (void*)&h2ow, (void*)&h2ob, (void*)&out, (void*)&ws, (void*)&tdec };
  hipLaunchCooperativeKernel((void*)rnn_persistent, dim3(NBLK), dim3(NTHR),
                             args, 0, stream);
}

// Round 2
// 30209.003 us; speedup vs baseline: 5.4526x; 5.4526x over previous
//
#include <hip/hip_runtime.h>

#define L_SEQ 4096
#define I_DIM 512
#define H_DIM 2048
#define O_DIM 512
#define NBLK  256
#define NTHR  512

typedef _Float16 h2 __attribute__((ext_vector_type(2)));
typedef float    f4 __attribute__((ext_vector_type(4)));

struct __attribute__((aligned(16))) H4 { h2 v[4]; };

#define ALOAD(p)     __hip_atomic_load((p), __ATOMIC_RELAXED, __HIP_MEMORY_SCOPE_AGENT)
#define ASTORE(p, v) __hip_atomic_store((p), (v), __ATOMIC_RELAXED, __HIP_MEMORY_SCOPE_AGENT)

__device__ __forceinline__ float fdot2_(h2 a, h2 b, float c) {
#if __has_builtin(__builtin_amdgcn_fdot2)
  return __builtin_amdgcn_fdot2(a, b, c, false);
#else
  return c + (float)a[0] * (float)b[0] + (float)a[1] * (float)b[1];
#endif
}

struct WRegs {
  h2 w[3][5][4];     // [gate r/z/n][k-segment 0..4][pair]  seg0 = W_ih, seg1..4 = W_hh
  float bi[3], bh[3];
};

__device__ __forceinline__ void load_weights(WRegs& W, int j, int lane,
    const float* __restrict__ w_ih, const float* __restrict__ w_hh,
    const float* __restrict__ b_ih, const float* __restrict__ b_hh) {
#pragma unroll
  for (int g = 0; g < 3; ++g) {
    const float* rih = w_ih + ((size_t)g * H_DIM + j) * I_DIM + lane * 8;
#pragma unroll
    for (int hh = 0; hh < 2; ++hh) {
      f4 a = *(const f4*)(rih + 4 * hh);
      W.w[g][0][2*hh+0] = h2{(_Float16)a[0], (_Float16)a[1]};
      W.w[g][0][2*hh+1] = h2{(_Float16)a[2], (_Float16)a[3]};
    }
    const float* rhh = w_hh + ((size_t)g * H_DIM + j) * H_DIM + lane * 8;
#pragma unroll
    for (int s = 1; s < 5; ++s) {
#pragma unroll
      for (int hh = 0; hh < 2; ++hh) {
        f4 a = *(const f4*)(rhh + (s - 1) * 512 + 4 * hh);
        W.w[g][s][2*hh+0] = h2{(_Float16)a[0], (_Float16)a[1]};
        W.w[g][s][2*hh+1] = h2{(_Float16)a[2], (_Float16)a[3]};
      }
    }
    W.bi[g] = b_ih[g * H_DIM + j];
    W.bh[g] = b_hh[g * H_DIM + j];
  }
}

// h staging: cross-block data -> MALL-direct (sc1) relaxed atomic loads,
// packed to f16 in LDS. No cache invalidate needed anywhere.
__device__ __forceinline__ void stage_h(_Float16* h_lds, const float* hsrc) {
  int t = threadIdx.x;
  if (t < 256) {
    const float* p = hsrc + t * 8;
    float a0 = ALOAD(p + 0), a1 = ALOAD(p + 1), a2 = ALOAD(p + 2), a3 = ALOAD(p + 3);
    float b0 = ALOAD(p + 4), b1 = ALOAD(p + 5), b2 = ALOAD(p + 6), b3 = ALOAD(p + 7);
    H4 pk;
    pk.v[0] = h2{(_Float16)a0, (_Float16)a1};
    pk.v[1] = h2{(_Float16)a2, (_Float16)a3};
    pk.v[2] = h2{(_Float16)b0, (_Float16)b1};
    pk.v[3] = h2{(_Float16)b2, (_Float16)b3};
    *(H4*)(h_lds + t * 8) = pk;
  }
}

__device__ __forceinline__ void dot_h(const WRegs& W, const _Float16* h_lds, int lane,
                                      float& ar, float& az, float& anh) {
#pragma unroll
  for (int s = 1; s < 5; ++s) {
    H4 hh = *(const H4*)(h_lds + (s - 1) * 512 + lane * 8);
#pragma unroll
    for (int q = 0; q < 4; ++q) {
      ar  = fdot2_(W.w[0][s][q], hh.v[q], ar);
      az  = fdot2_(W.w[1][s][q], hh.v[q], az);
      anh = fdot2_(W.w[2][s][q], hh.v[q], anh);
    }
  }
}

__device__ __forceinline__ void wave_red4(float& a, float& b, float& c, float& d) {
#pragma unroll
  for (int off = 32; off > 0; off >>= 1) {
    a += __shfl_xor(a, off, 64);
    b += __shfl_xor(b, off, 64);
    c += __shfl_xor(c, off, 64);
    d += __shfl_xor(d, off, 64);
  }
}

// Fence-free grid barrier. All cross-block data moves via sc1 write-through
// atomics; each wave drains its own in-flight stores (s_waitcnt 0) before
// s_barrier, then thread 0 publishes its flag. NO buffer_wbl2 / buffer_inv.
__device__ __forceinline__ void gbar(int* flags, int blk, int phase) {
  __builtin_amdgcn_s_waitcnt(0);     // this wave's write-through stores are at MALL
  __syncthreads();
  if (threadIdx.x == 0)
    ASTORE(&flags[blk], phase + 1);
  if (threadIdx.x < NBLK) {
    while (ALOAD(&flags[threadIdx.x]) <= phase)
      __builtin_amdgcn_s_sleep(1);
  }
  __syncthreads();
}

__global__ void __launch_bounds__(NTHR, 2) rnn_persistent(
    const float* __restrict__ input_,
    const float* __restrict__ ewih, const float* __restrict__ ewhh,
    const float* __restrict__ ebih, const float* __restrict__ ebhh,
    const float* __restrict__ dwih, const float* __restrict__ dwhh,
    const float* __restrict__ dbih, const float* __restrict__ dbhh,
    const float* __restrict__ h2ow, const float* __restrict__ h2ob,
    float* __restrict__ out, char* __restrict__ ws, int tdec)
{
  __shared__ alignas(16) _Float16 h_lds[H_DIM];
  __shared__ float red[16];
  __shared__ int   sidx[16];
  __shared__ int   idx_sh;

  int*   flags  = (int*)ws;
  float* hbuf0  = (float*)(ws + 1024);
  float* hbuf1  = hbuf0 + H_DIM;
  float* logits = (float*)(ws + 1024 + 2 * H_DIM * 4);
  int*   idxp   = (int*)(ws + 1024 + 2 * H_DIM * 4 + O_DIM * 4);

  const int tid  = threadIdx.x;
  const int lane = tid & 63;
  const int wid  = tid >> 6;
  const int blk  = blockIdx.x;
  const int j    = blk * 8 + wid;     // hidden unit owned by this wave

  WRegs W;
  load_weights(W, j, lane, ewih, ewhh, ebih, ebhh);

  float hold = 0.f;   // exact fp32 carry of h_j
  int phase = 0;

  // ---------------- encoder ----------------
  for (int t = 0; t < L_SEQ; ++t) {
    float* hin  = (t & 1) ? hbuf1 : hbuf0;
    float* hout = (t & 1) ? hbuf0 : hbuf1;
    stage_h(h_lds, hin);
    const float* xr = input_ + (size_t)t * I_DIM + lane * 8;
    f4 xa = *(const f4*)xr;
    f4 xb = *(const f4*)(xr + 4);
    h2 xv[4] = { h2{(_Float16)xa[0], (_Float16)xa[1]}, h2{(_Float16)xa[2], (_Float16)xa[3]},
                 h2{(_Float16)xb[0], (_Float16)xb[1]}, h2{(_Float16)xb[2], (_Float16)xb[3]} };
    __syncthreads();

    float ar = 0.f, az = 0.f, anx = 0.f, anh = 0.f;
#pragma unroll
    for (int q = 0; q < 4; ++q) {
      ar  = fdot2_(W.w[0][0][q], xv[q], ar);
      az  = fdot2_(W.w[1][0][q], xv[q], az);
      anx = fdot2_(W.w[2][0][q], xv[q], anx);
    }
    dot_h(W, h_lds, lane, ar, az, anh);
    wave_red4(ar, az, anx, anh);

    float r = 1.f / (1.f + __expf(-(ar + W.bi[0] + W.bh[0])));
    float z = 1.f / (1.f + __expf(-(az + W.bi[1] + W.bh[1])));
    float n = tanhf(anx + W.bi[2] + r * (anh + W.bh[2]));
    hold = (1.f - z) * n + z * hold;
    if (lane == 0)
      ASTORE(&hout[j], hold);
    gbar(flags, blk, phase++);
  }

  // ---------------- decoder ----------------
  load_weights(W, j, lane, dwih, dwhh, dbih, dbhh);
  int db = 0;   // L_SEQ even -> h_enc sits in hbuf0

  for (int d = 0; d < tdec; ++d) {
    float* hin  = db ? hbuf1 : hbuf0;
    float* hout = db ? hbuf0 : hbuf1;

    if (tid == 0) idx_sh = (d > 0) ? ALOAD(idxp) : -1;   // one-hot feedback
    stage_h(h_lds, hin);
    __syncthreads();
    const int idx = idx_sh;

    float ar = 0.f, az = 0.f, anx = 0.f, anh = 0.f;
    if (idx >= 0 && lane == (idx >> 3)) {
      const int qq = (idx & 7) >> 1;
      const int pp = idx & 1;
#pragma unroll
      for (int q = 0; q < 4; ++q) if (q == qq) {
        ar  += pp ? (float)W.w[0][0][q][1] : (float)W.w[0][0][q][0];
        az  += pp ? (float)W.w[1][0][q][1] : (float)W.w[1][0][q][0];
        anx += pp ? (float)W.w[2][0][q][1] : (float)W.w[2][0][q][0];
      }
    }
    dot_h(W, h_lds, lane, ar, az, anh);
    wave_red4(ar, az, anx, anh);

    float r = 1.f / (1.f + __expf(-(ar + W.bi[0] + W.bh[0])));
    float z = 1.f / (1.f + __expf(-(az + W.bi[1] + W.bh[1])));
    float n = tanhf(anx + W.bi[2] + r * (anh + W.bh[2]));
    hold = (1.f - z) * n + z * hold;
    if (lane == 0)
      ASTORE(&hout[j], hold);
    gbar(flags, blk, phase++);

    // ---- logits: rows 2*blk, 2*blk+1 of h2o (512 rows over 256 blocks) ----
    {
      const int row = 2 * blk + (tid >> 8);
      const int kk  = (tid & 255) * 8;
      const float* wrow = h2ow + (size_t)row * H_DIM + kk;
      const float* hrow = hout + kk;
      f4 wa = *(const f4*)wrow, wb = *(const f4*)(wrow + 4);
      float h0 = ALOAD(hrow + 0), h1 = ALOAD(hrow + 1), h2v = ALOAD(hrow + 2), h3 = ALOAD(hrow + 3);
      float h4 = ALOAD(hrow + 4), h5 = ALOAD(hrow + 5), h6 = ALOAD(hrow + 6), h7 = ALOAD(hrow + 7);
      float s = wa[0]*h0 + wa[1]*h1 + wa[2]*h2v + wa[3]*h3
              + wb[0]*h4 + wb[1]*h5 + wb[2]*h6 + wb[3]*h7;
#pragma unroll
      for (int off = 32; off > 0; off >>= 1) s += __shfl_xor(s, off, 64);
      if (lane == 0) red[wid] = s;
      __syncthreads();
      if (tid == 0) {
        float v = red[0] + red[1] + red[2] + red[3] + h2ob[2 * blk];
        ASTORE(&logits[2 * blk], v);
      }
      if (tid == 256) {
        float v = red[4] + red[5] + red[6] + red[7] + h2ob[2 * blk + 1];
        ASTORE(&logits[2 * blk + 1], v);
      }
    }
    gbar(flags, blk, phase++);

    // ---- log-softmax + argmax on block 0 ----
    if (blk == 0) {
      float v = ALOAD(&logits[tid]);
      float m = v; int mi = tid;
#pragma unroll
      for (int off = 32; off > 0; off >>= 1) {
        float om = __shfl_xor(m, off, 64);
        int   oi = __shfl_xor(mi, off, 64);
        if (om > m || (om == m && oi < mi)) { m = om; mi = oi; }
      }
      if (lane == 0) { red[wid] = m; sidx[wid] = mi; }
      __syncthreads();
      float M = red[0]; int MI = sidx[0];
#pragma unroll
      for (int w2 = 1; w2 < 8; ++w2)
        if (red[w2] > M || (red[w2] == M && sidx[w2] < MI)) { M = red[w2]; MI = sidx[w2]; }
      float e = __expf(v - M);
      float ss = e;
#pragma unroll
      for (int off = 32; off > 0; off >>= 1) ss += __shfl_xor(ss, off, 64);
      __syncthreads();
      if (lane == 0) red[wid] = ss;
      __syncthreads();
      float S = red[0] + red[1] + red[2] + red[3] + red[4] + red[5] + red[6] + red[7];
      out[(size_t)d * O_DIM + tid] = v - M - __logf(S);
      if (tid == 0)
        ASTORE(idxp, MI);
    }
    gbar(flags, blk, phase++);
    db ^= 1;
  }
}

extern "C" void kernel_launch(void* const* d_in, const int* in_sizes, int n_in,
                              void* d_out, int out_size, void* d_ws, size_t ws_size,
                              hipStream_t stream) {
  const float* input_ = (const float*)d_in[0];
  const float* ewih   = (const float*)d_in[1];
  const float* ewhh   = (const float*)d_in[2];
  const float* ebih   = (const float*)d_in[3];
  const float* ebhh   = (const float*)d_in[4];
  const float* dwih   = (const float*)d_in[5];
  const float* dwhh   = (const float*)d_in[6];
  const float* dbih   = (const float*)d_in[7];
  const float* dbhh   = (const float*)d_in[8];
  const float* h2ow   = (const float*)d_in[9];
  const float* h2ob   = (const float*)d_in[10];
  float* out = (float*)d_out;
  char*  ws  = (char*)d_ws;
  int tdec = out_size / O_DIM;   // 30

  // zero flags + h double-buffer + logits + idx (ws is re-poisoned every launch)
  hipMemsetAsync(d_ws, 0, 1024 + 2 * H_DIM * 4 + O_DIM * 4 + 64, stream);

  void* args[] = { (void*)&input_, (void*)&ewih, (void*)&ewhh, (void*)&ebih, (void*)&ebhh,
                   (void*)&dwih, (void*)&dwhh, (void*)&dbih, (void*)&dbhh,
                   (void*)&h2ow, (void*)&h2ob, (void*)&out, (void*)&ws, (void*)&tdec };
  hipLaunchCooperativeKernel((void*)rnn_persistent, dim3(NBLK), dim3(NTHR),
                             args, 0, stream);
}

// Round 3
// 19656.213 us; speedup vs baseline: 8.3799x; 1.5369x over previous
//
#include <hip/hip_runtime.h>

#define L_SEQ 4096
#define I_DIM 512
#define H_DIM 2048
#define O_DIM 512
#define NBLK  256
#define NTHR  512
#define BUFS  4          // >=3 makes tag-flow skew-safe with no barriers at all

typedef _Float16 h2 __attribute__((ext_vector_type(2)));
typedef float    f4 __attribute__((ext_vector_type(4)));
typedef unsigned int       u32;
typedef unsigned long long u64;

struct __attribute__((aligned(16))) H4 { h2 v[4]; };

#define ALOAD32(p)     __hip_atomic_load((p), __ATOMIC_RELAXED, __HIP_MEMORY_SCOPE_AGENT)
#define ASTORE32(p, v) __hip_atomic_store((p), (v), __ATOMIC_RELAXED, __HIP_MEMORY_SCOPE_AGENT)
#define ALOAD64(p)     __hip_atomic_load((p), __ATOMIC_RELAXED, __HIP_MEMORY_SCOPE_AGENT)
#define ASTORE64(p, v) __hip_atomic_store((p), (v), __ATOMIC_RELAXED, __HIP_MEMORY_SCOPE_AGENT)

__device__ __forceinline__ float fdot2_(h2 a, h2 b, float c) {
#if __has_builtin(__builtin_amdgcn_fdot2)
  return __builtin_amdgcn_fdot2(a, b, c, false);
#else
  return c + (float)a[0] * (float)b[0] + (float)a[1] * (float)b[1];
#endif
}

// pack {tag16 | f16(h)} into one atomically-stored dword: the tag IS the flag.
__device__ __forceinline__ u32 packh(u32 tag, float v) {
  union { _Float16 h; unsigned short u; } c; c.h = (_Float16)v;
  return (tag << 16) | (u32)c.u;
}
__device__ __forceinline__ float f16bits_to_f32(u32 w) {
  union { unsigned short u; _Float16 h; } c; c.u = (unsigned short)(w & 0xffff);
  return (float)c.h;
}
__device__ __forceinline__ u64 pack64(u32 tag, float v) {
  union { float f; u32 u; } c; c.f = v;
  return ((u64)tag << 32) | c.u;
}
__device__ __forceinline__ float val64(u64 pk) {
  union { u32 u; float f; } c; c.u = (u32)pk; return c.f;
}
__device__ __forceinline__ u32 tag64(u64 pk) { return (u32)(pk >> 32); }

struct WRegs {
  h2 w[3][5][4];     // [gate r/z/n][k-segment 0..4][pair]  seg0 = W_ih, seg1..4 = W_hh
  float bi[3], bh[3];
};

__device__ __forceinline__ void load_weights(WRegs& W, int j, int lane,
    const float* __restrict__ w_ih, const float* __restrict__ w_hh,
    const float* __restrict__ b_ih, const float* __restrict__ b_hh) {
#pragma unroll
  for (int g = 0; g < 3; ++g) {
    const float* rih = w_ih + ((size_t)g * H_DIM + j) * I_DIM + lane * 8;
#pragma unroll
    for (int hh = 0; hh < 2; ++hh) {
      f4 a = *(const f4*)(rih + 4 * hh);
      W.w[g][0][2*hh+0] = h2{(_Float16)a[0], (_Float16)a[1]};
      W.w[g][0][2*hh+1] = h2{(_Float16)a[2], (_Float16)a[3]};
    }
    const float* rhh = w_hh + ((size_t)g * H_DIM + j) * H_DIM + lane * 8;
#pragma unroll
    for (int s = 1; s < 5; ++s) {
#pragma unroll
      for (int hh = 0; hh < 2; ++hh) {
        f4 a = *(const f4*)(rhh + (s - 1) * 512 + 4 * hh);
        W.w[g][s][2*hh+0] = h2{(_Float16)a[0], (_Float16)a[1]};
        W.w[g][s][2*hh+1] = h2{(_Float16)a[2], (_Float16)a[3]};
      }
    }
    W.bi[g] = b_ih[g * H_DIM + j];
    W.bh[g] = b_hh[g * H_DIM + j];
  }
}

// Tag-synchronized h staging: all 512 threads poll 4 dwords each (j=4t..4t+3),
// then drop the f16 payloads into LDS. Data arrival IS the barrier.
__device__ __forceinline__ void stage4(_Float16* h_lds, const u32* p, u32 tag, int tid) {
  u32 v0 = ALOAD32(p + 0), v1 = ALOAD32(p + 1), v2 = ALOAD32(p + 2), v3 = ALOAD32(p + 3);
  while ((((v0 >> 16) ^ tag) | ((v1 >> 16) ^ tag) |
          ((v2 >> 16) ^ tag) | ((v3 >> 16) ^ tag)) != 0u) {
    __builtin_amdgcn_s_sleep(1);
    if ((v0 >> 16) != tag) v0 = ALOAD32(p + 0);
    if ((v1 >> 16) != tag) v1 = ALOAD32(p + 1);
    if ((v2 >> 16) != tag) v2 = ALOAD32(p + 2);
    if ((v3 >> 16) != tag) v3 = ALOAD32(p + 3);
  }
  union { struct { u32 a, b; } w; } pk;
  pk.w.a = (v0 & 0xffffu) | (v1 << 16);
  pk.w.b = (v2 & 0xffffu) | (v3 << 16);
  *(u32*)(h_lds + tid * 4)     = pk.w.a;
  *(u32*)(h_lds + tid * 4 + 2) = pk.w.b;
}

__device__ __forceinline__ void dot_h(const WRegs& W, const _Float16* h_lds, int lane,
                                      float& ar, float& az, float& anh) {
#pragma unroll
  for (int s = 1; s < 5; ++s) {
    H4 hh = *(const H4*)(h_lds + (s - 1) * 512 + lane * 8);
#pragma unroll
    for (int q = 0; q < 4; ++q) {
      ar  = fdot2_(W.w[0][s][q], hh.v[q], ar);
      az  = fdot2_(W.w[1][s][q], hh.v[q], az);
      anh = fdot2_(W.w[2][s][q], hh.v[q], anh);
    }
  }
}

__device__ __forceinline__ void wave_red4(float& a, float& b, float& c, float& d) {
#pragma unroll
  for (int off = 32; off > 0; off >>= 1) {
    a += __shfl_xor(a, off, 64);
    b += __shfl_xor(b, off, 64);
    c += __shfl_xor(c, off, 64);
    d += __shfl_xor(d, off, 64);
  }
}

__global__ void __launch_bounds__(NTHR, 2) rnn_persistent(
    const float* __restrict__ input_,
    const float* __restrict__ ewih, const float* __restrict__ ewhh,
    const float* __restrict__ ebih, const float* __restrict__ ebhh,
    const float* __restrict__ dwih, const float* __restrict__ dwhh,
    const float* __restrict__ dbih, const float* __restrict__ dbhh,
    const float* __restrict__ h2ow, const float* __restrict__ h2ob,
    float* __restrict__ out, char* __restrict__ ws, int tdec)
{
  __shared__ alignas(16) _Float16 h_lds[H_DIM];
  __shared__ float redm[8], reds[8];
  __shared__ int   sidx[8];
  __shared__ int   idx_sh;

  u32* hexch  = (u32*)ws;                    // BUFS * 2048 * 4B = 32 KB
  u64* logits = (u64*)(ws + BUFS * H_DIM * 4);
  u64* idxp   = (u64*)(ws + BUFS * H_DIM * 4 + O_DIM * 8);

  const int tid  = threadIdx.x;
  const int lane = tid & 63;
  const int wid  = tid >> 6;
  const int blk  = blockIdx.x;
  const int j    = blk * 8 + wid;     // hidden unit owned by this wave

  WRegs W;
  load_weights(W, j, lane, ewih, ewhh, ebih, ebhh);

  float hold = 0.f;   // exact fp32 carry of h_j

  // ---------------- encoder ----------------
  // iter t: consume h(t) [tag t, slot t%BUFS], produce h(t+1) [tag t+1].
  // memset gives {tag0, 0.0f16} = exactly h(0)=0 for t=0.
  for (u32 t = 0; t < L_SEQ; ++t) {
    const float* xr = input_ + (size_t)t * I_DIM + lane * 8;
    f4 xa = *(const f4*)xr;                 // issued before the poll; latency hides
    f4 xb = *(const f4*)(xr + 4);

    stage4(h_lds, hexch + (t % BUFS) * H_DIM + tid * 4, t & 0xffffu, tid);
    __syncthreads();

    h2 xv[4] = { h2{(_Float16)xa[0], (_Float16)xa[1]}, h2{(_Float16)xa[2], (_Float16)xa[3]},
                 h2{(_Float16)xb[0], (_Float16)xb[1]}, h2{(_Float16)xb[2], (_Float16)xb[3]} };

    float ar = 0.f, az = 0.f, anx = 0.f, anh = 0.f;
#pragma unroll
    for (int q = 0; q < 4; ++q) {
      ar  = fdot2_(W.w[0][0][q], xv[q], ar);
      az  = fdot2_(W.w[1][0][q], xv[q], az);
      anx = fdot2_(W.w[2][0][q], xv[q], anx);
    }
    dot_h(W, h_lds, lane, ar, az, anh);
    wave_red4(ar, az, anx, anh);

    float r = 1.f / (1.f + __expf(-(ar + W.bi[0] + W.bh[0])));
    float z = 1.f / (1.f + __expf(-(az + W.bi[1] + W.bh[1])));
    float n = tanhf(anx + W.bi[2] + r * (anh + W.bh[2]));
    hold = (1.f - z) * n + z * hold;
    if (lane == 0)
      ASTORE32(&hexch[((t + 1) % BUFS) * H_DIM + j], packh((t + 1) & 0xffffu, hold));
    __syncthreads();   // LDS reuse guard (next iter overwrites h_lds)
  }

  // ---------------- decoder ----------------
  load_weights(W, j, lane, dwih, dwhh, dbih, dbhh);

  for (int d = 0; d < tdec; ++d) {
    const u32 t = L_SEQ + (u32)d;

    if (tid == 0) {
      int ix = -1;
      if (d > 0) {                          // poll one-hot index {tag d}
        u64 pk = ALOAD64(idxp);
        while (tag64(pk) != (u32)d) { __builtin_amdgcn_s_sleep(1); pk = ALOAD64(idxp); }
        ix = (int)(u32)pk;
      }
      idx_sh = ix;
    }
    stage4(h_lds, hexch + (t % BUFS) * H_DIM + tid * 4, t & 0xffffu, tid);
    __syncthreads();
    const int idx = idx_sh;

    float ar = 0.f, az = 0.f, anx = 0.f, anh = 0.f;
    if (idx >= 0 && lane == (idx >> 3)) {
      const int qq = (idx & 7) >> 1;
      const int pp = idx & 1;
#pragma unroll
      for (int q = 0; q < 4; ++q) if (q == qq) {
        ar  += pp ? (float)W.w[0][0][q][1] : (float)W.w[0][0][q][0];
        az  += pp ? (float)W.w[1][0][q][1] : (float)W.w[1][0][q][0];
        anx += pp ? (float)W.w[2][0][q][1] : (float)W.w[2][0][q][0];
      }
    }
    dot_h(W, h_lds, lane, ar, az, anh);
    wave_red4(ar, az, anx, anh);

    float r = 1.f / (1.f + __expf(-(ar + W.bi[0] + W.bh[0])));
    float z = 1.f / (1.f + __expf(-(az + W.bi[1] + W.bh[1])));
    float n = tanhf(anx + W.bi[2] + r * (anh + W.bh[2]));
    hold = (1.f - z) * n + z * hold;
    if (lane == 0)
      ASTORE32(&hexch[((t + 1) % BUFS) * H_DIM + j], packh((t + 1) & 0xffffu, hold));

    // ---- logits: rows 2*blk, 2*blk+1; consume h(t+1) via tagged dwords ----
    {
      const int row = 2 * blk + (tid >> 8);
      const int kk  = (tid & 255) * 8;
      const float* wrow = h2ow + (size_t)row * H_DIM + kk;
      f4 wa = *(const f4*)wrow, wb = *(const f4*)(wrow + 4);
      const u32* hp = hexch + ((t + 1) % BUFS) * H_DIM + kk;
      const u32 htag = (t + 1) & 0xffffu;
      u32 g[8];
#pragma unroll
      for (int k = 0; k < 8; ++k) g[k] = ALOAD32(hp + k);
      for (;;) {
        u32 bad = 0;
#pragma unroll
        for (int k = 0; k < 8; ++k) bad |= (g[k] >> 16) ^ htag;
        if (!bad) break;
        __builtin_amdgcn_s_sleep(1);
#pragma unroll
        for (int k = 0; k < 8; ++k) if ((g[k] >> 16) != htag) g[k] = ALOAD32(hp + k);
      }
      float s = wa[0]*f16bits_to_f32(g[0]) + wa[1]*f16bits_to_f32(g[1])
              + wa[2]*f16bits_to_f32(g[2]) + wa[3]*f16bits_to_f32(g[3])
              + wb[0]*f16bits_to_f32(g[4]) + wb[1]*f16bits_to_f32(g[5])
              + wb[2]*f16bits_to_f32(g[6]) + wb[3]*f16bits_to_f32(g[7]);
#pragma unroll
      for (int off = 32; off > 0; off >>= 1) s += __shfl_xor(s, off, 64);
      if (lane == 0) redm[wid] = s;
      __syncthreads();
      if (tid == 0)
        ASTORE64(&logits[2 * blk],
                 pack64((u32)(d + 1), redm[0] + redm[1] + redm[2] + redm[3] + h2ob[2 * blk]));
      if (tid == 256)
        ASTORE64(&logits[2 * blk + 1],
                 pack64((u32)(d + 1), redm[4] + redm[5] + redm[6] + redm[7] + h2ob[2 * blk + 1]));
    }
    __syncthreads();

    // ---- log-softmax + argmax on block 0 (consumes tagged logits) ----
    if (blk == 0) {
      u64 pk = ALOAD64(&logits[tid]);
      while (tag64(pk) != (u32)(d + 1)) { __builtin_amdgcn_s_sleep(1); pk = ALOAD64(&logits[tid]); }
      float v = val64(pk);
      float m = v; int mi = tid;
#pragma unroll
      for (int off = 32; off > 0; off >>= 1) {
        float om = __shfl_xor(m, off, 64);
        int   oi = __shfl_xor(mi, off, 64);
        if (om > m || (om == m && oi < mi)) { m = om; mi = oi; }
      }
      if (lane == 0) { redm[wid] = m; sidx[wid] = mi; }
      __syncthreads();
      float M = redm[0]; int MI = sidx[0];
#pragma unroll
      for (int w2 = 1; w2 < 8; ++w2)
        if (redm[w2] > M || (redm[w2] == M && sidx[w2] < MI)) { M = redm[w2]; MI = sidx[w2]; }
      float ss = __expf(v - M);
#pragma unroll
      for (int off = 32; off > 0; off >>= 1) ss += __shfl_xor(ss, off, 64);
      if (lane == 0) reds[wid] = ss;
      __syncthreads();
      float S = reds[0] + reds[1] + reds[2] + reds[3]
              + reds[4] + reds[5] + reds[6] + reds[7];
      out[(size_t)d * O_DIM + tid] = v - M - __logf(S);
      if (tid == 0)
        ASTORE64(idxp, pack64((u32)(d + 1), (u32)MI));
    }
    __syncthreads();   // LDS reuse guard
  }
}

extern "C" void kernel_launch(void* const* d_in, const int* in_sizes, int n_in,
                              void* d_out, int out_size, void* d_ws, size_t ws_size,
                              hipStream_t stream) {
  const float* input_ = (const float*)d_in[0];
  const float* ewih   = (const float*)d_in[1];
  const float* ewhh   = (const float*)d_in[2];
  const float* ebih   = (const float*)d_in[3];
  const float* ebhh   = (const float*)d_in[4];
  const float* dwih   = (const float*)d_in[5];
  const float* dwhh   = (const float*)d_in[6];
  const float* dbih   = (const float*)d_in[7];
  const float* dbhh   = (const float*)d_in[8];
  const float* h2ow   = (const float*)d_in[9];
  const float* h2ob   = (const float*)d_in[10];
  float* out = (float*)d_out;
  char*  ws  = (char*)d_ws;
  int tdec = out_size / O_DIM;   // 30

  // zero the exchange region: tags reset to 0 (= valid h(0)=0 for iter 0)
  hipMemsetAsync(d_ws, 0, BUFS * H_DIM * 4 + O_DIM * 8 + 64, stream);

  void* args[] = { (void*)&input_, (void*)&ewih, (void*)&ewhh, (void*)&ebih, (void*)&ebhh,
                   (void*)&dwih, (void*)&dwhh, (void*)&dbih, (void*)&dbhh,
                   (void*)&h2ow, (void*)&h2ob, (void*)&out, (void*)&ws, (void*)&tdec };
  hipLaunchCooperativeKernel((void*)rnn_persistent, dim3(NBLK), dim3(NTHR),
                             args, 0, stream);
}